// Round 4
// baseline (1343.284 us; speedup 1.0000x reference)
//
#include <hip/hip_runtime.h>
#include <hip/hip_bf16.h>
#include <stdint.h>

typedef __attribute__((ext_vector_type(8))) short short8;
typedef __attribute__((ext_vector_type(4))) float f32x4;
typedef __attribute__((ext_vector_type(4))) unsigned u32x4;
typedef unsigned long long u64;

#define DI static __device__ __forceinline__

DI unsigned short f2b(float f){
  unsigned u = __float_as_uint(f);
  u = (u + 0x7FFFu + ((u >> 16) & 1u)) >> 16;
  return (unsigned short)u;
}
DI float sigm(float x){ return 1.0f / (1.0f + __expf(-x)); }
DI float tanh_(float x){ return 1.0f - 2.0f / (__expf(2.0f*x) + 1.0f); } // safe at +/-inf
DI unsigned pk2(unsigned short a, unsigned short b){ return (unsigned)a | ((unsigned)b << 16); }

// ---- embedding gather: Xbf[r' = t*64+b][256] = bf16(emb[input[b][t]])
__global__ void k_gather(const int* __restrict__ inp, const float* __restrict__ emb,
                         unsigned short* __restrict__ Xbf){
  int r = blockIdx.x;            // r' = t*64 + b
  int t = r >> 6, b = r & 63;
  int idx = inp[b*128 + t];
  float v = emb[(size_t)idx*256 + threadIdx.x];
  Xbf[(size_t)r*256 + threadIdx.x] = f2b(v);
}

// ---- transpose src[R][C] (rows row0..row0+R-1, ld) -> dst[n(C)][R]
// BF: bf16 output. REORD: gate-interleave columns n' = (c&255)*4 + (c>>8)
template<int BF, int REORD>
__global__ void k_transpose(const float* __restrict__ src, void* __restrict__ dst,
                            int R, int C, int ld, int row0){
  __shared__ float tile[32][33];
  int tx = threadIdx.x, ty = threadIdx.y;
  int x = blockIdx.x*32 + tx;
  for (int i = 0; i < 4; i++){
    int y = blockIdx.y*32 + ty + i*8;
    if (x < C && y < R) tile[ty + i*8][tx] = src[(size_t)(row0 + y)*ld + x];
  }
  __syncthreads();
  int y2 = blockIdx.y*32 + tx;                 // R index
  for (int i = 0; i < 4; i++){
    int x2 = blockIdx.x*32 + ty + i*8;         // C index
    if (x2 < C && y2 < R){
      float v = tile[tx][ty + i*8];
      int n = REORD ? ((x2 & 255)*4 + (x2 >> 8)) : x2;
      if (BF) ((unsigned short*)dst)[(size_t)n*R + y2] = f2b(v);
      else    ((float*)dst)[(size_t)n*R + y2] = v;
    }
  }
}

// ---- MFMA GEMM (m97 pattern): C[m][n] = sum_k A[m][k]*Bt[n][k], A/Bt bf16 [rows][256]
// global_load_lds width-16 staging, XOR-swizzled LDS slots (unpadded 64-short rows).
// EPI 0: Z0x store (+bias b0 with gate-reorder un-map), rows r'=(t,b) -> Z0x[t][n'][b]
// EPI 1: fused softmax partial: S[row] += sum exp(logit+bias); LT[row] = logit_tgt
template<int EPI>
__launch_bounds__(256, 2)
__global__ void k_gemm(const unsigned short* __restrict__ A, const unsigned short* __restrict__ Bt,
                       float* __restrict__ outZ, const float* __restrict__ bias,
                       const int* __restrict__ tgt, float* __restrict__ S, float* __restrict__ LT){
  __shared__ unsigned short As[128*64];
  __shared__ unsigned short Bs[128*64];
  __shared__ int tgt_s[128];
  const int m0 = blockIdx.y*128, n0 = blockIdx.x*128;
  const int tid = threadIdx.x;
  const int w = tid >> 6, l = tid & 63;
  const int quad = l >> 4, l15 = l & 15;
  const int wm = (w >> 1)*64, wn = (w & 1)*64;
  const int lrow = l >> 3, ls = l & 7;         // lane -> (row-in-group, slot)
  f32x4 acc[4][4] = {};
  if (EPI == 1 && tid < 128) tgt_s[tid] = tgt[m0 + tid];

  for (int k0 = 0; k0 < 256; k0 += 64){
    #pragma unroll
    for (int it = 0; it < 4; it++){
      int row = it*32 + w*8 + lrow;
      int csrc = ls ^ (row & 7);               // XOR swizzle: slot s holds chunk s^(row&7)
      __builtin_amdgcn_global_load_lds(
        (const __attribute__((address_space(1))) unsigned*)&A[(size_t)(m0+row)*256 + k0 + csrc*8],
        (__attribute__((address_space(3))) unsigned*)&As[(it*32 + w*8)*64], 16, 0, 0);
      __builtin_amdgcn_global_load_lds(
        (const __attribute__((address_space(1))) unsigned*)&Bt[(size_t)(n0+row)*256 + k0 + csrc*8],
        (__attribute__((address_space(3))) unsigned*)&Bs[(it*32 + w*8)*64], 16, 0, 0);
    }
    __syncthreads();
    #pragma unroll
    for (int ks = 0; ks < 64; ks += 32){
      const int cki = (ks >> 3) + quad;        // k-chunk index 0..7
      short8 af[4], bfr[4];
      #pragma unroll
      for (int i = 0; i < 4; i++){
        int row = wm + i*16 + l15;
        af[i]  = *(short8*)&As[row*64 + (cki ^ (row & 7))*8];
      }
      #pragma unroll
      for (int j = 0; j < 4; j++){
        int row = wn + j*16 + l15;
        bfr[j] = *(short8*)&Bs[row*64 + (cki ^ (row & 7))*8];
      }
      #pragma unroll
      for (int i = 0; i < 4; i++)
        #pragma unroll
        for (int j = 0; j < 4; j++)
          acc[i][j] = __builtin_amdgcn_mfma_f32_16x16x32_bf16(af[i], bfr[j], acc[i][j], 0, 0, 0);
    }
    __syncthreads();
  }

  if (EPI == 0){
    #pragma unroll
    for (int i = 0; i < 4; i++){
      int mg = m0 + wm + i*16 + quad*4;        // rows mg..mg+3 in this reg quad
      int t = mg >> 6, b = mg & 63;
      #pragma unroll
      for (int j = 0; j < 4; j++){
        int ng = n0 + wn + j*16 + l15;         // n' (gate-interleaved)
        float bb = bias[(ng & 3)*256 + (ng >> 2)];
        f32x4 v = acc[i][j];
        v[0] += bb; v[1] += bb; v[2] += bb; v[3] += bb;
        *(f32x4*)&outZ[((size_t)t*1024 + ng)*64 + b] = v;
      }
    }
  } else {
    #pragma unroll
    for (int i = 0; i < 4; i++){
      float rs[4] = {0.f,0.f,0.f,0.f};
      #pragma unroll
      for (int j = 0; j < 4; j++){
        int ng = n0 + wn + j*16 + l15;
        float bb = bias[ng];
        f32x4 v = acc[i][j];
        #pragma unroll
        for (int r = 0; r < 4; r++){
          float e = v[r] + bb;
          int mloc = wm + i*16 + quad*4 + r;
          if (tgt_s[mloc] == ng) LT[m0 + mloc] = e;
          rs[r] += __expf(e);
        }
      }
      #pragma unroll
      for (int r = 0; r < 4; r++){
        float s = rs[r];
        s += __shfl_xor(s, 1, 16);
        s += __shfl_xor(s, 2, 16);
        s += __shfl_xor(s, 4, 16);
        s += __shfl_xor(s, 8, 16);
        if (l15 == 0) atomicAdd(&S[m0 + wm + i*16 + quad*4 + r], s);
      }
    }
  }
}

// ---- XCD-L2 tagged-packet staging.
// Packet p (payload u32 = 2 bf16, tag u32) lives at global u64 offset
//   addr64(p0) = ((p0>>1)&255)*32 + (p0>>9)*2   for even p0 (16B chunk = packets p0,p0+1)
// Consumer thread tid loads 16 chunks at byte voff=tid*256, imm k*16 -> packets p0=2*tid+512*k.
// All loads/stores use sc0 (bypass L1, coherent in this XCD's L2).
DI void stage_xcd(const u64* __restrict__ src, unsigned* __restrict__ dst4,
                  int tid, unsigned tagexp){
  u32x4 o0,o1,o2,o3,o4,o5,o6,o7,o8,o9,o10,o11,o12,o13,o14,o15;
  const unsigned vo = tid*256;
  for (;;){
    asm volatile(
      "global_load_dwordx4 %[a0], %[vo], %[sb] offset:0 sc0\n\t"
      "global_load_dwordx4 %[a1], %[vo], %[sb] offset:16 sc0\n\t"
      "global_load_dwordx4 %[a2], %[vo], %[sb] offset:32 sc0\n\t"
      "global_load_dwordx4 %[a3], %[vo], %[sb] offset:48 sc0\n\t"
      "global_load_dwordx4 %[a4], %[vo], %[sb] offset:64 sc0\n\t"
      "global_load_dwordx4 %[a5], %[vo], %[sb] offset:80 sc0\n\t"
      "global_load_dwordx4 %[a6], %[vo], %[sb] offset:96 sc0\n\t"
      "global_load_dwordx4 %[a7], %[vo], %[sb] offset:112 sc0\n\t"
      "global_load_dwordx4 %[a8], %[vo], %[sb] offset:128 sc0\n\t"
      "global_load_dwordx4 %[a9], %[vo], %[sb] offset:144 sc0\n\t"
      "global_load_dwordx4 %[a10], %[vo], %[sb] offset:160 sc0\n\t"
      "global_load_dwordx4 %[a11], %[vo], %[sb] offset:176 sc0\n\t"
      "global_load_dwordx4 %[a12], %[vo], %[sb] offset:192 sc0\n\t"
      "global_load_dwordx4 %[a13], %[vo], %[sb] offset:208 sc0\n\t"
      "global_load_dwordx4 %[a14], %[vo], %[sb] offset:224 sc0\n\t"
      "global_load_dwordx4 %[a15], %[vo], %[sb] offset:240 sc0\n\t"
      "s_waitcnt vmcnt(0)"
      : [a0]"=&v"(o0),[a1]"=&v"(o1),[a2]"=&v"(o2),[a3]"=&v"(o3),
        [a4]"=&v"(o4),[a5]"=&v"(o5),[a6]"=&v"(o6),[a7]"=&v"(o7),
        [a8]"=&v"(o8),[a9]"=&v"(o9),[a10]"=&v"(o10),[a11]"=&v"(o11),
        [a12]"=&v"(o12),[a13]"=&v"(o13),[a14]"=&v"(o14),[a15]"=&v"(o15)
      : [vo]"v"(vo), [sb]"s"(src)
      : "memory");
    unsigned bad =
      (o0[1]^tagexp)|(o0[3]^tagexp)|(o1[1]^tagexp)|(o1[3]^tagexp)|
      (o2[1]^tagexp)|(o2[3]^tagexp)|(o3[1]^tagexp)|(o3[3]^tagexp)|
      (o4[1]^tagexp)|(o4[3]^tagexp)|(o5[1]^tagexp)|(o5[3]^tagexp)|
      (o6[1]^tagexp)|(o6[3]^tagexp)|(o7[1]^tagexp)|(o7[3]^tagexp)|
      (o8[1]^tagexp)|(o8[3]^tagexp)|(o9[1]^tagexp)|(o9[3]^tagexp)|
      (o10[1]^tagexp)|(o10[3]^tagexp)|(o11[1]^tagexp)|(o11[3]^tagexp)|
      (o12[1]^tagexp)|(o12[3]^tagexp)|(o13[1]^tagexp)|(o13[3]^tagexp)|
      (o14[1]^tagexp)|(o14[3]^tagexp)|(o15[1]^tagexp)|(o15[3]^tagexp);
    if (bad == 0u) break;
    __builtin_amdgcn_s_sleep(1);
  }
  uint2* d = (uint2*)dst4;                     // uint2 idx = tid + k*256  (u32 idx 2tid+512k = p0)
  d[tid +  0*256] = make_uint2(o0[0],  o0[2]);
  d[tid +  1*256] = make_uint2(o1[0],  o1[2]);
  d[tid +  2*256] = make_uint2(o2[0],  o2[2]);
  d[tid +  3*256] = make_uint2(o3[0],  o3[2]);
  d[tid +  4*256] = make_uint2(o4[0],  o4[2]);
  d[tid +  5*256] = make_uint2(o5[0],  o5[2]);
  d[tid +  6*256] = make_uint2(o6[0],  o6[2]);
  d[tid +  7*256] = make_uint2(o7[0],  o7[2]);
  d[tid +  8*256] = make_uint2(o8[0],  o8[2]);
  d[tid +  9*256] = make_uint2(o9[0],  o9[2]);
  d[tid + 10*256] = make_uint2(o10[0], o10[2]);
  d[tid + 11*256] = make_uint2(o11[0], o11[2]);
  d[tid + 12*256] = make_uint2(o12[0], o12[2]);
  d[tid + 13*256] = make_uint2(o13[0], o13[2]);
  d[tid + 14*256] = make_uint2(o14[0], o14[2]);
  d[tid + 15*256] = make_uint2(o15[0], o15[2]);
}

DI void st16_sc0(u64* p, u32x4 v){
  asm volatile("global_store_dwordx4 %0, %1, off sc0" :: "v"(p), "v"(v) : "memory");
}

// ---- persistent 2-layer LSTM on ONE XCD. 256 WGs launched; after registration the
// 24 lowest-ranked WGs on the argmax XCD work (8 layer0 + 16 layer1), rest exit.
// h exchanged as tagged packets through the shared XCD L2 (sc0 ops). Weights in regs.
__launch_bounds__(256, 1)
__global__ void k_lstm(const float* __restrict__ Z0x,          // [128 t][1024 n'][64 b] f32 (b0 folded)
                       const unsigned short* __restrict__ W0h, // [1024 n'][256 k] bf16
                       const unsigned short* __restrict__ W1,  // [1024 n'][512 k] bf16
                       const float* __restrict__ b1,
                       u64* __restrict__ h0h,                  // [128 t][8192 pkt]
                       u64* __restrict__ h1h,                  // [128 t][8192 pkt]
                       unsigned short* __restrict__ H1bf,      // [b*128+t][256 u]
                       unsigned* __restrict__ reg){            // cnt[8], total
  __shared__ __align__(16) char smraw[65536];        // union: h-frag stage | z scratch
  unsigned short* hs = (unsigned short*)smraw;
  unsigned* hs4 = (unsigned*)smraw;
  float* zl = (float*)smraw;
  __shared__ int s_role;

  const int tid = threadIdx.x;

  // ---- registration: find 24 co-XCD workgroups
  {
    unsigned xcc;
    asm volatile("s_getreg_b32 %0, hwreg(HW_REG_XCC_ID)" : "=s"(xcc));
    if (tid == 0){
      unsigned r = atomicAdd(&reg[xcc & 7u], 1u);
      __threadfence();                         // cnt visible before total
      atomicAdd(&reg[8], 1u);
      while (__hip_atomic_load(&reg[8], __ATOMIC_RELAXED, __HIP_MEMORY_SCOPE_AGENT) < 256u)
        __builtin_amdgcn_s_sleep(2);
      __threadfence();
      unsigned best = 0; unsigned bx = 0;
      for (unsigned i = 0; i < 8; i++){
        unsigned c = __hip_atomic_load(&reg[i], __ATOMIC_RELAXED, __HIP_MEMORY_SCOPE_AGENT);
        if (c > best){ best = c; bx = i; }
      }
      s_role = ((xcc & 7u) == bx && r < 24u) ? (int)r : -1;
    }
    __syncthreads();
  }
  const int role = s_role;
  if (role < 0) return;

  const bool L0 = (role < 8);
  const int w = tid >> 6, l = tid & 63, quad = l >> 4, l15 = l & 15;
  const int b = tid & 63;

  short8 bw[16];               // persistent weight fragments (64 VGPRs)
  float c_st[8];
  float b1r[16];
  #pragma unroll
  for (int i = 0; i < 8; i++) c_st[i] = 0.f;

  if (L0){
    const int n0 = role*128;
    #pragma unroll
    for (int j = 0; j < 2; j++)
      #pragma unroll
      for (int ks = 0; ks < 8; ks++)
        bw[j*8+ks] = *(const short8*)&W0h[(size_t)(n0 + w*32 + j*16 + l15)*256 + ks*32 + quad*8];
  } else {
    const int n0 = (role-8)*64;
    #pragma unroll
    for (int ks = 0; ks < 16; ks++)
      bw[ks] = *(const short8*)&W1[(size_t)(n0 + w*16 + l15)*512 + ks*32 + quad*8];
    const int u0 = (role-8)*16, ul0 = w*4;
    #pragma unroll
    for (int ul = 0; ul < 4; ul++)
      #pragma unroll
      for (int g = 0; g < 4; g++)
        b1r[ul*4+g] = b1[g*256 + u0 + ul0 + ul];
  }

  if (L0){
    for (int t = 0; t < 128; t++){
      const int n0 = role*128;
      f32x4 acc[4][2];
      #pragma unroll
      for (int i = 0; i < 4; i++)
        #pragma unroll
        for (int j = 0; j < 2; j++){
          int cl = w*32 + j*16 + l15;
          acc[i][j] = *(const f32x4*)&Z0x[((size_t)t*1024 + n0 + cl)*64 + i*16 + quad*4];
        }
      if (t > 0){
        stage_xcd(h0h + (size_t)(t-1)*8192, hs4, tid, (unsigned)t);
        __syncthreads();
        #pragma unroll
        for (int ks = 0; ks < 8; ks++){
          short8 a[4];
          #pragma unroll
          for (int i = 0; i < 4; i++)
            a[i] = *(const short8*)&hs[(((ks*4+quad)*64) + i*16 + l15)*8];
          #pragma unroll
          for (int i = 0; i < 4; i++)
            #pragma unroll
            for (int j = 0; j < 2; j++)
              acc[i][j] = __builtin_amdgcn_mfma_f32_16x16x32_bf16(a[i], bw[j*8+ks], acc[i][j], 0, 0, 0);
        }
        __syncthreads();                       // hs reads done; zl aliases hs
      }
      #pragma unroll
      for (int i = 0; i < 4; i++)
        #pragma unroll
        for (int j = 0; j < 2; j++){
          int cl = w*32 + j*16 + l15;
          *(f32x4*)&zl[cl*68 + i*16 + quad*4] = acc[i][j];
        }
      __syncthreads();
      // cell update: 8 units per thread
      const int ul0 = w*8;
      unsigned short hout[8];
      #pragma unroll
      for (int ui = 0; ui < 8; ui++){
        int cc = (ul0 + ui)*4;
        float zi = zl[(cc+0)*68 + b], zj = zl[(cc+1)*68 + b];
        float zf = zl[(cc+2)*68 + b], zo = zl[(cc+3)*68 + b];
        float c = c_st[ui]*sigm(zf + 1.0f) + sigm(zi)*tanh_(zj);
        c_st[ui] = c;
        hout[ui] = f2b(tanh_(c)*sigm(zo));
      }
      // publish 4 packets = 2 chunks, tag = t+1
      {
        const int kb = role*4 + w;
        const unsigned tag = (unsigned)(t+1);
        const size_t c0 = (size_t)t*8192 + (size_t)((kb&1)*128 + 2*b)*32 + (size_t)(kb>>1)*2;
        u32x4 v1; v1[0]=pk2(hout[0],hout[1]); v1[1]=tag; v1[2]=pk2(hout[2],hout[3]); v1[3]=tag;
        u32x4 v2; v2[0]=pk2(hout[4],hout[5]); v2[1]=tag; v2[2]=pk2(hout[6],hout[7]); v2[3]=tag;
        st16_sc0(h0h + c0, v1);
        st16_sc0(h0h + c0 + 32, v2);
      }
      __syncthreads();                         // zl reads done before next-iter staging
    }
  } else {
    for (int t = 0; t < 128; t++){
      f32x4 acc[4];
      #pragma unroll
      for (int i = 0; i < 4; i++) acc[i] = (f32x4){0.f,0.f,0.f,0.f};
      if (t > 0){
        // h1(t-1) is long ready: stage + MFMA its half first
        stage_xcd(h1h + (size_t)(t-1)*8192, hs4 + 8192, tid, (unsigned)t);
        __syncthreads();
        #pragma unroll
        for (int ks = 8; ks < 16; ks++){       // kb 32..63 -> hs shorts 16384..32767
          short8 a[4];
          #pragma unroll
          for (int i = 0; i < 4; i++)
            a[i] = *(const short8*)&hs[(((ks*4+quad)*64) + i*16 + l15)*8];
          #pragma unroll
          for (int i = 0; i < 4; i++)
            acc[i] = __builtin_amdgcn_mfma_f32_16x16x32_bf16(a[i], bw[ks], acc[i], 0, 0, 0);
        }
      }
      // now poll the critical h0(t)
      stage_xcd(h0h + (size_t)t*8192, hs4, tid, (unsigned)(t+1));
      __syncthreads();
      #pragma unroll
      for (int ks = 0; ks < 8; ks++){
        short8 a[4];
        #pragma unroll
        for (int i = 0; i < 4; i++)
          a[i] = *(const short8*)&hs[(((ks*4+quad)*64) + i*16 + l15)*8];
        #pragma unroll
        for (int i = 0; i < 4; i++)
          acc[i] = __builtin_amdgcn_mfma_f32_16x16x32_bf16(a[i], bw[ks], acc[i], 0, 0, 0);
      }
      __syncthreads();                         // hs reads done; zl aliases hs
      {
        int cl = w*16 + l15;
        #pragma unroll
        for (int i = 0; i < 4; i++)
          *(f32x4*)&zl[cl*68 + i*16 + quad*4] = acc[i];
      }
      __syncthreads();
      // cell update: 4 units per thread
      const int u0 = (role-8)*16, ul0 = w*4;
      unsigned short hout[4];
      #pragma unroll
      for (int ui = 0; ui < 4; ui++){
        int cc = (ul0 + ui)*4;
        float zi = zl[(cc+0)*68 + b] + b1r[ui*4+0];
        float zj = zl[(cc+1)*68 + b] + b1r[ui*4+1];
        float zf = zl[(cc+2)*68 + b] + b1r[ui*4+2];
        float zo = zl[(cc+3)*68 + b] + b1r[ui*4+3];
        float c = c_st[ui]*sigm(zf + 1.0f) + sigm(zi)*tanh_(zj);
        c_st[ui] = c;
        hout[ui] = f2b(tanh_(c)*sigm(zo));
      }
      {
        const int u = u0 + ul0;                // multiple of 4
        const int kb = u >> 3;
        const unsigned tag = (unsigned)(t+1);
        const size_t c0 = (size_t)t*8192
                        + (size_t)((kb&1)*128 + 2*b + ((u&4)>>2))*32 + (size_t)(kb>>1)*2;
        u32x4 v; v[0]=pk2(hout[0],hout[1]); v[1]=tag; v[2]=pk2(hout[2],hout[3]); v[3]=tag;
        st16_sc0(h1h + c0, v);
        *(uint2*)&H1bf[((size_t)b*128 + t)*256 + u] = *(const uint2*)hout;   // plain store
      }
      __syncthreads();                         // zl reads done before next-iter staging
    }
  }
}

// ---- final reduce: cost = mean(log(S) - LT)
__global__ void k_reduce(const float* __restrict__ S, const float* __restrict__ LT,
                         float* __restrict__ out){
  __shared__ float red[256];
  float s = 0.f;
  for (int r = threadIdx.x; r < 8192; r += 256) s += __logf(S[r]) - LT[r];
  red[threadIdx.x] = s;
  __syncthreads();
  for (int st = 128; st > 0; st >>= 1){
    if (threadIdx.x < st) red[threadIdx.x] += red[threadIdx.x + st];
    __syncthreads();
  }
  if (threadIdx.x == 0) out[0] = red[0] / 8192.0f;
}

extern "C" void kernel_launch(void* const* d_in, const int* in_sizes, int n_in,
                              void* d_out, int out_size, void* d_ws, size_t ws_size,
                              hipStream_t stream){
  const int*   input   = (const int*)  d_in[0];
  const int*   targets = (const int*)  d_in[1];
  const float* emb     = (const float*)d_in[2];
  const float* W0      = (const float*)d_in[3];
  const float* b0      = (const float*)d_in[4];
  const float* W1      = (const float*)d_in[5];
  const float* b1      = (const float*)d_in[6];
  const float* Wsm     = (const float*)d_in[7];
  const float* sb      = (const float*)d_in[8];

  char* ws = (char*)d_ws;
  size_t off = 0;
  auto alloc = [&](size_t bytes)->char*{
    char* p = ws + off; off += (bytes + 255) & ~(size_t)255; return p;
  };
  unsigned short* Xbf  = (unsigned short*)alloc(8192ull*256*2);
  unsigned short* W0xT = (unsigned short*)alloc(1024ull*256*2);
  unsigned short* W0hT = (unsigned short*)alloc(1024ull*256*2);
  unsigned short* W1T  = (unsigned short*)alloc(1024ull*512*2);
  unsigned short* WsT  = (unsigned short*)alloc(16000ull*256*2);
  float*          Z0x  = (float*)         alloc(8192ull*1024*4);
  u64*            h0h  = (u64*)           alloc(128ull*8192*8);   // tagged history
  u64*            h1h  = (u64*)           alloc(128ull*8192*8);
  unsigned short* H1bf = (unsigned short*)alloc(8192ull*256*2);
  float*          S    = (float*)         alloc(8192ull*4);
  float*          LT   = (float*)         alloc(8192ull*4);
  unsigned*       reg  = (unsigned*)      alloc(256);

  hipMemsetAsync(S,   0, 8192ull*4, stream);
  hipMemsetAsync(reg, 0, 256, stream);        // registration counters

  k_gather<<<dim3(8192), dim3(256), 0, stream>>>(input, emb, Xbf);
  k_transpose<1,1><<<dim3(32, 8),  dim3(32,8), 0, stream>>>(W0,  (void*)W0xT, 256, 1024, 1024, 0);
  k_transpose<1,1><<<dim3(32, 8),  dim3(32,8), 0, stream>>>(W0,  (void*)W0hT, 256, 1024, 1024, 256);
  k_transpose<1,1><<<dim3(32, 16), dim3(32,8), 0, stream>>>(W1,  (void*)W1T,  512, 1024, 1024, 0);
  k_transpose<1,0><<<dim3(500, 8), dim3(32,8), 0, stream>>>(Wsm, (void*)WsT,  256, 16000, 16000, 0);

  // Z0x = X @ W0[:256,:] + b0   (M=8192 r'=(t,b), N=1024 n', K=256)
  k_gemm<0><<<dim3(8, 64), dim3(256), 0, stream>>>(Xbf, W0xT, Z0x, b0, nullptr, nullptr, nullptr);

  // persistent LSTM: 256 WGs cooperative; 24 workers self-select onto one XCD
  void* kargs[] = { (void*)&Z0x, (void*)&W0hT, (void*)&W1T, (void*)&b1,
                    (void*)&h0h, (void*)&h1h, (void*)&H1bf, (void*)&reg };
  hipLaunchCooperativeKernel((void*)k_lstm, dim3(256), dim3(256), kargs, 0, stream);

  // fused projection + log-softmax partials (M=8192 r=(b,t), N=16000, K=256)
  k_gemm<1><<<dim3(125, 64), dim3(256), 0, stream>>>(H1bf, WsT, nullptr, sb, targets, S, LT);

  k_reduce<<<dim3(1), dim3(256), 0, stream>>>(S, LT, (float*)d_out);
}

// Round 5
// 854.972 us; speedup vs baseline: 1.5711x; 1.5711x over previous
//
#include <hip/hip_runtime.h>
#include <hip/hip_bf16.h>
#include <stdint.h>

typedef __attribute__((ext_vector_type(8))) short short8;
typedef __attribute__((ext_vector_type(4))) float f32x4;
typedef unsigned long long u64;

#define DI static __device__ __forceinline__

DI unsigned short f2b(float f){
  unsigned u = __float_as_uint(f);
  u = (u + 0x7FFFu + ((u >> 16) & 1u)) >> 16;
  return (unsigned short)u;
}
DI float sigm(float x){ return 1.0f / (1.0f + __expf(-x)); }
DI float tanh_(float x){ return 1.0f - 2.0f / (__expf(2.0f*x) + 1.0f); } // safe at +/-inf
DI unsigned pk2(unsigned short a, unsigned short b){ return (unsigned)a | ((unsigned)b << 16); }

// ---- embedding gather: Xbf[r' = t*64+b][256] = bf16(emb[input[b][t]])
__global__ void k_gather(const int* __restrict__ inp, const float* __restrict__ emb,
                         unsigned short* __restrict__ Xbf){
  int r = blockIdx.x;            // r' = t*64 + b
  int t = r >> 6, b = r & 63;
  int idx = inp[b*128 + t];
  float v = emb[(size_t)idx*256 + threadIdx.x];
  Xbf[(size_t)r*256 + threadIdx.x] = f2b(v);
}

// ---- transpose src[R][C] (rows row0..row0+R-1, ld) -> dst[n(C)][R]
// BF: bf16 output. REORD: gate-interleave columns n' = (c&255)*4 + (c>>8)
template<int BF, int REORD>
__global__ void k_transpose(const float* __restrict__ src, void* __restrict__ dst,
                            int R, int C, int ld, int row0){
  __shared__ float tile[32][33];
  int tx = threadIdx.x, ty = threadIdx.y;
  int x = blockIdx.x*32 + tx;
  for (int i = 0; i < 4; i++){
    int y = blockIdx.y*32 + ty + i*8;
    if (x < C && y < R) tile[ty + i*8][tx] = src[(size_t)(row0 + y)*ld + x];
  }
  __syncthreads();
  int y2 = blockIdx.y*32 + tx;                 // R index
  for (int i = 0; i < 4; i++){
    int x2 = blockIdx.x*32 + ty + i*8;         // C index
    if (x2 < C && y2 < R){
      float v = tile[tx][ty + i*8];
      int n = REORD ? ((x2 & 255)*4 + (x2 >> 8)) : x2;
      if (BF) ((unsigned short*)dst)[(size_t)n*R + y2] = f2b(v);
      else    ((float*)dst)[(size_t)n*R + y2] = v;
    }
  }
}

// ---- MFMA GEMM (m97 pattern): C[m][n] = sum_k A[m][k]*Bt[n][k], A/Bt bf16 [rows][256]
// Block mapping: m0 = blockIdx.x (fast) so consecutive blocks share the same B-tile (L2 reuse).
// EPI 0: Z0x store (+bias b0 with gate-reorder un-map), rows r'=(t,b) -> Z0x[t][n'][b]
// EPI 1: fused softmax partial: S[row] += sum exp(logit+bias); LT[row] = logit_tgt
template<int EPI>
__launch_bounds__(256, 2)
__global__ void k_gemm(const unsigned short* __restrict__ A, const unsigned short* __restrict__ Bt,
                       float* __restrict__ outZ, const float* __restrict__ bias,
                       const int* __restrict__ tgt, float* __restrict__ S, float* __restrict__ LT){
  __shared__ unsigned short As[128*64];
  __shared__ unsigned short Bs[128*64];
  __shared__ int tgt_s[128];
  const int m0 = blockIdx.x*128, n0 = blockIdx.y*128;
  const int tid = threadIdx.x;
  const int w = tid >> 6, l = tid & 63;
  const int quad = l >> 4, l15 = l & 15;
  const int wm = (w >> 1)*64, wn = (w & 1)*64;
  const int lrow = l >> 3, ls = l & 7;         // lane -> (row-in-group, slot)
  f32x4 acc[4][4] = {};
  if (EPI == 1 && tid < 128) tgt_s[tid] = tgt[m0 + tid];

  for (int k0 = 0; k0 < 256; k0 += 64){
    #pragma unroll
    for (int it = 0; it < 4; it++){
      int row = it*32 + w*8 + lrow;
      int csrc = ls ^ (row & 7);               // XOR swizzle: slot s holds chunk s^(row&7)
      __builtin_amdgcn_global_load_lds(
        (const __attribute__((address_space(1))) unsigned*)&A[(size_t)(m0+row)*256 + k0 + csrc*8],
        (__attribute__((address_space(3))) unsigned*)&As[(it*32 + w*8)*64], 16, 0, 0);
      __builtin_amdgcn_global_load_lds(
        (const __attribute__((address_space(1))) unsigned*)&Bt[(size_t)(n0+row)*256 + k0 + csrc*8],
        (__attribute__((address_space(3))) unsigned*)&Bs[(it*32 + w*8)*64], 16, 0, 0);
    }
    __syncthreads();
    #pragma unroll
    for (int ks = 0; ks < 64; ks += 32){
      const int cki = (ks >> 3) + quad;        // k-chunk index 0..7
      short8 af[4], bfr[4];
      #pragma unroll
      for (int i = 0; i < 4; i++){
        int row = wm + i*16 + l15;
        af[i]  = *(short8*)&As[row*64 + (cki ^ (row & 7))*8];
      }
      #pragma unroll
      for (int j = 0; j < 4; j++){
        int row = wn + j*16 + l15;
        bfr[j] = *(short8*)&Bs[row*64 + (cki ^ (row & 7))*8];
      }
      #pragma unroll
      for (int i = 0; i < 4; i++)
        #pragma unroll
        for (int j = 0; j < 4; j++)
          acc[i][j] = __builtin_amdgcn_mfma_f32_16x16x32_bf16(af[i], bfr[j], acc[i][j], 0, 0, 0);
    }
    __syncthreads();
  }

  if (EPI == 0){
    #pragma unroll
    for (int i = 0; i < 4; i++){
      int mg = m0 + wm + i*16 + quad*4;        // rows mg..mg+3 in this reg quad
      int t = mg >> 6, b = mg & 63;
      #pragma unroll
      for (int j = 0; j < 4; j++){
        int ng = n0 + wn + j*16 + l15;         // n' (gate-interleaved)
        float bb = bias[(ng & 3)*256 + (ng >> 2)];
        f32x4 v = acc[i][j];
        v[0] += bb; v[1] += bb; v[2] += bb; v[3] += bb;
        *(f32x4*)&outZ[((size_t)t*1024 + ng)*64 + b] = v;
      }
    }
  } else {
    #pragma unroll
    for (int i = 0; i < 4; i++){
      float rs[4] = {0.f,0.f,0.f,0.f};
      #pragma unroll
      for (int j = 0; j < 4; j++){
        int ng = n0 + wn + j*16 + l15;
        float bb = bias[ng];
        f32x4 v = acc[i][j];
        #pragma unroll
        for (int r = 0; r < 4; r++){
          float e = v[r] + bb;
          int mloc = wm + i*16 + quad*4 + r;
          if (tgt_s[mloc] == ng) LT[m0 + mloc] = e;
          rs[r] += __expf(e);
        }
      }
      #pragma unroll
      for (int r = 0; r < 4; r++){
        float s = rs[r];
        s += __shfl_xor(s, 1, 16);
        s += __shfl_xor(s, 2, 16);
        s += __shfl_xor(s, 4, 16);
        s += __shfl_xor(s, 8, 16);
        if (l15 == 0) atomicAdd(&S[m0 + wm + i*16 + quad*4 + r], s);
      }
    }
  }
}

// ---- persistent 2-layer LSTM, 24 WGs cooperative, flag-notify dataflow.
// WG 0..7: layer0 (32 units each); WG 8..23: layer1 (16 units each). Weights in regs.
// Protocol per step t: producers store h (agent scope, write-through LLC),
// s_waitcnt(0), __syncthreads, tid0 atomicAdd(flag[t]). Consumers: tid0 spins on a
// single 4B agent load of flag[t] until quorum, then ONE plain global_load_lds bulk
// stage (addresses fresh per t -> no stale-L2 hazard; kernel-start acquire cleared L2).
__launch_bounds__(256, 1)
__global__ void k_lstm(const float* __restrict__ Z0x,          // [128 t][1024 n'][64 b] f32 (b0 folded)
                       const unsigned short* __restrict__ W0h, // [1024 n'][256 k] bf16
                       const unsigned short* __restrict__ W1,  // [1024 n'][512 k] bf16
                       const float* __restrict__ b1,
                       u64* __restrict__ h0h,                  // [128 t][2048] = [kb][b][8] bf16
                       u64* __restrict__ h1h,                  // [128 t][2048]
                       unsigned short* __restrict__ H1bf,      // [b*128+t][256 u]
                       unsigned* __restrict__ flag0,           // [128]
                       unsigned* __restrict__ flag1){          // [128]
  __shared__ __align__(16) char smraw[65536];        // union: h-frag stage | z scratch
  unsigned short* hs = (unsigned short*)smraw;
  float* zl = (float*)smraw;

  const int wg = blockIdx.x;
  const bool L0 = (wg < 8);
  const int tid = threadIdx.x;
  const int w = tid >> 6, l = tid & 63, quad = l >> 4, l15 = l & 15;
  const int b = tid & 63;
  const unsigned short* h0s = (const unsigned short*)h0h;
  const unsigned short* h1s = (const unsigned short*)h1h;

  short8 bw[16];               // persistent weight fragments (64 VGPRs)
  float c_st[8];
  float b1r[16];
  #pragma unroll
  for (int i = 0; i < 8; i++) c_st[i] = 0.f;

  if (L0){
    const int n0 = wg*128;
    #pragma unroll
    for (int j = 0; j < 2; j++)
      #pragma unroll
      for (int ks = 0; ks < 8; ks++)
        bw[j*8+ks] = *(const short8*)&W0h[(size_t)(n0 + w*32 + j*16 + l15)*256 + ks*32 + quad*8];
  } else {
    const int n0 = (wg-8)*64;
    #pragma unroll
    for (int ks = 0; ks < 16; ks++)
      bw[ks] = *(const short8*)&W1[(size_t)(n0 + w*16 + l15)*512 + ks*32 + quad*8];
    const int u0 = (wg-8)*16, ul0 = w*4;
    #pragma unroll
    for (int ul = 0; ul < 4; ul++)
      #pragma unroll
      for (int g = 0; g < 4; g++)
        b1r[ul*4+g] = b1[g*256 + u0 + ul0 + ul];
  }

  if (L0){
    const int n0 = wg*128;
    for (int t = 0; t < 128; t++){
      f32x4 acc[4][2];
      #pragma unroll
      for (int i = 0; i < 4; i++)
        #pragma unroll
        for (int j = 0; j < 2; j++){
          int cl = w*32 + j*16 + l15;
          acc[i][j] = *(const f32x4*)&Z0x[((size_t)t*1024 + n0 + cl)*64 + i*16 + quad*4];
        }
      if (t > 0){
        if (tid == 0)
          while (__hip_atomic_load(flag0 + (t-1), __ATOMIC_RELAXED, __HIP_MEMORY_SCOPE_AGENT) < 8u)
            __builtin_amdgcn_s_sleep(1);
        __syncthreads();
        #pragma unroll
        for (int it = 0; it < 8; it++){
          int c = it*256 + w*64 + l;
          __builtin_amdgcn_global_load_lds(
            (const __attribute__((address_space(1))) unsigned*)&h0s[(size_t)(t-1)*16384 + (size_t)c*8],
            (__attribute__((address_space(3))) unsigned*)&hs[(it*256 + w*64)*8], 16, 0, 0);
        }
        __builtin_amdgcn_s_waitcnt(0);
        __syncthreads();
        #pragma unroll
        for (int ks = 0; ks < 8; ks++){
          short8 a[4];
          #pragma unroll
          for (int i = 0; i < 4; i++)
            a[i] = *(const short8*)&hs[(((ks*4+quad)*64) + i*16 + l15)*8];
          #pragma unroll
          for (int i = 0; i < 4; i++)
            #pragma unroll
            for (int j = 0; j < 2; j++)
              acc[i][j] = __builtin_amdgcn_mfma_f32_16x16x32_bf16(a[i], bw[j*8+ks], acc[i][j], 0, 0, 0);
        }
        __syncthreads();                       // hs reads done; zl aliases hs
      }
      #pragma unroll
      for (int i = 0; i < 4; i++)
        #pragma unroll
        for (int j = 0; j < 2; j++){
          int cl = w*32 + j*16 + l15;
          *(f32x4*)&zl[cl*68 + i*16 + quad*4] = acc[i][j];
        }
      __syncthreads();
      // cell update: 8 units per thread
      const int ul0 = w*8;
      unsigned short hout[8];
      #pragma unroll
      for (int ui = 0; ui < 8; ui++){
        int cc = (ul0 + ui)*4;
        float zi = zl[(cc+0)*68 + b], zj = zl[(cc+1)*68 + b];
        float zf = zl[(cc+2)*68 + b], zo = zl[(cc+3)*68 + b];
        float c = c_st[ui]*sigm(zf + 1.0f) + sigm(zi)*tanh_(zj);
        c_st[ui] = c;
        hout[ui] = f2b(tanh_(c)*sigm(zo));
      }
      // publish (agent scope -> LLC write-through), then notify
      {
        u64 v0 = (u64)pk2(hout[0],hout[1]) | ((u64)pk2(hout[2],hout[3]) << 32);
        u64 v1 = (u64)pk2(hout[4],hout[5]) | ((u64)pk2(hout[6],hout[7]) << 32);
        size_t pbase = (size_t)t*2048 + ((size_t)(wg*4 + w)*64 + b)*2;
        __hip_atomic_store(h0h + pbase,     v0, __ATOMIC_RELAXED, __HIP_MEMORY_SCOPE_AGENT);
        __hip_atomic_store(h0h + pbase + 1, v1, __ATOMIC_RELAXED, __HIP_MEMORY_SCOPE_AGENT);
      }
      __builtin_amdgcn_s_waitcnt(0);           // stores LLC-acked
      __syncthreads();                         // all threads' stores acked; zl reads done
      if (tid == 0)
        __hip_atomic_fetch_add(flag0 + t, 1u, __ATOMIC_RELAXED, __HIP_MEMORY_SCOPE_AGENT);
    }
  } else {
    const int u0 = (wg-8)*16, ul0 = w*4;
    for (int t = 0; t < 128; t++){
      f32x4 acc[4];
      #pragma unroll
      for (int i = 0; i < 4; i++) acc[i] = (f32x4){0.f,0.f,0.f,0.f};
      if (t > 0){
        // h1(t-1): ready (we produced it); stage + MFMA its half while layer0 works on h0(t)
        if (tid == 0)
          while (__hip_atomic_load(flag1 + (t-1), __ATOMIC_RELAXED, __HIP_MEMORY_SCOPE_AGENT) < 16u)
            __builtin_amdgcn_s_sleep(1);
        __syncthreads();
        #pragma unroll
        for (int it = 0; it < 8; it++){
          int c = it*256 + w*64 + l;
          __builtin_amdgcn_global_load_lds(
            (const __attribute__((address_space(1))) unsigned*)&h1s[(size_t)(t-1)*16384 + (size_t)c*8],
            (__attribute__((address_space(3))) unsigned*)&hs[16384 + (it*256 + w*64)*8], 16, 0, 0);
        }
        __builtin_amdgcn_s_waitcnt(0);
        __syncthreads();
        #pragma unroll
        for (int ks = 8; ks < 16; ks++){       // kb 32..63 -> hs shorts 16384..32767
          short8 a[4];
          #pragma unroll
          for (int i = 0; i < 4; i++)
            a[i] = *(const short8*)&hs[(((ks*4+quad)*64) + i*16 + l15)*8];
          #pragma unroll
          for (int i = 0; i < 4; i++)
            acc[i] = __builtin_amdgcn_mfma_f32_16x16x32_bf16(a[i], bw[ks], acc[i], 0, 0, 0);
        }
      }
      // critical h0(t)
      if (tid == 0)
        while (__hip_atomic_load(flag0 + t, __ATOMIC_RELAXED, __HIP_MEMORY_SCOPE_AGENT) < 8u)
          __builtin_amdgcn_s_sleep(1);
      __syncthreads();
      #pragma unroll
      for (int it = 0; it < 8; it++){
        int c = it*256 + w*64 + l;
        __builtin_amdgcn_global_load_lds(
          (const __attribute__((address_space(1))) unsigned*)&h0s[(size_t)t*16384 + (size_t)c*8],
          (__attribute__((address_space(3))) unsigned*)&hs[(it*256 + w*64)*8], 16, 0, 0);
      }
      __builtin_amdgcn_s_waitcnt(0);
      __syncthreads();
      #pragma unroll
      for (int ks = 0; ks < 8; ks++){
        short8 a[4];
        #pragma unroll
        for (int i = 0; i < 4; i++)
          a[i] = *(const short8*)&hs[(((ks*4+quad)*64) + i*16 + l15)*8];
        #pragma unroll
        for (int i = 0; i < 4; i++)
          acc[i] = __builtin_amdgcn_mfma_f32_16x16x32_bf16(a[i], bw[ks], acc[i], 0, 0, 0);
      }
      __syncthreads();                         // hs reads done; zl aliases hs
      {
        int cl = w*16 + l15;
        #pragma unroll
        for (int i = 0; i < 4; i++)
          *(f32x4*)&zl[cl*68 + i*16 + quad*4] = acc[i];
      }
      __syncthreads();
      // cell update: 4 units per thread
      unsigned short hout[4];
      #pragma unroll
      for (int ui = 0; ui < 4; ui++){
        int cc = (ul0 + ui)*4;
        float zi = zl[(cc+0)*68 + b] + b1r[ui*4+0];
        float zj = zl[(cc+1)*68 + b] + b1r[ui*4+1];
        float zf = zl[(cc+2)*68 + b] + b1r[ui*4+2];
        float zo = zl[(cc+3)*68 + b] + b1r[ui*4+3];
        float c = c_st[ui]*sigm(zf + 1.0f) + sigm(zi)*tanh_(zj);
        c_st[ui] = c;
        hout[ui] = f2b(tanh_(c)*sigm(zo));
      }
      {
        const int u = u0 + ul0;                // multiple of 4
        u64 v = (u64)pk2(hout[0],hout[1]) | ((u64)pk2(hout[2],hout[3]) << 32);
        size_t pbase = (size_t)t*2048 + ((size_t)(u >> 3)*64 + b)*2 + ((u & 4) >> 2);
        __hip_atomic_store(h1h + pbase, v, __ATOMIC_RELAXED, __HIP_MEMORY_SCOPE_AGENT);
        *(uint2*)&H1bf[((size_t)b*128 + t)*256 + u] = *(const uint2*)hout;   // plain store
      }
      __builtin_amdgcn_s_waitcnt(0);
      __syncthreads();
      if (tid == 0)
        __hip_atomic_fetch_add(flag1 + t, 1u, __ATOMIC_RELAXED, __HIP_MEMORY_SCOPE_AGENT);
    }
  }
}

// ---- final reduce: cost = mean(log(S) - LT)
__global__ void k_reduce(const float* __restrict__ S, const float* __restrict__ LT,
                         float* __restrict__ out){
  __shared__ float red[256];
  float s = 0.f;
  for (int r = threadIdx.x; r < 8192; r += 256) s += __logf(S[r]) - LT[r];
  red[threadIdx.x] = s;
  __syncthreads();
  for (int st = 128; st > 0; st >>= 1){
    if (threadIdx.x < st) red[threadIdx.x] += red[threadIdx.x + st];
    __syncthreads();
  }
  if (threadIdx.x == 0) out[0] = red[0] / 8192.0f;
}

extern "C" void kernel_launch(void* const* d_in, const int* in_sizes, int n_in,
                              void* d_out, int out_size, void* d_ws, size_t ws_size,
                              hipStream_t stream){
  const int*   input   = (const int*)  d_in[0];
  const int*   targets = (const int*)  d_in[1];
  const float* emb     = (const float*)d_in[2];
  const float* W0      = (const float*)d_in[3];
  const float* b0      = (const float*)d_in[4];
  const float* W1      = (const float*)d_in[5];
  const float* b1      = (const float*)d_in[6];
  const float* Wsm     = (const float*)d_in[7];
  const float* sb      = (const float*)d_in[8];

  char* ws = (char*)d_ws;
  size_t off = 0;
  auto alloc = [&](size_t bytes)->char*{
    char* p = ws + off; off += (bytes + 255) & ~(size_t)255; return p;
  };
  unsigned short* Xbf  = (unsigned short*)alloc(8192ull*256*2);
  unsigned short* W0xT = (unsigned short*)alloc(1024ull*256*2);
  unsigned short* W0hT = (unsigned short*)alloc(1024ull*256*2);
  unsigned short* W1T  = (unsigned short*)alloc(1024ull*512*2);
  unsigned short* WsT  = (unsigned short*)alloc(16000ull*256*2);
  float*          Z0x  = (float*)         alloc(8192ull*1024*4);
  u64*            h0h  = (u64*)           alloc(128ull*2048*8);   // h0 history [t][kb][b][8]
  u64*            h1h  = (u64*)           alloc(128ull*2048*8);
  unsigned short* H1bf = (unsigned short*)alloc(8192ull*256*2);
  float*          S    = (float*)         alloc(8192ull*4);
  float*          LT   = (float*)         alloc(8192ull*4);
  unsigned*       flag0= (unsigned*)      alloc(128*4);
  unsigned*       flag1= (unsigned*)      alloc(128*4);

  hipMemsetAsync(S,     0, 8192ull*4, stream);
  hipMemsetAsync(flag0, 0, 2*((128*4 + 255) & ~255), stream);  // flag0+flag1 contiguous

  k_gather<<<dim3(8192), dim3(256), 0, stream>>>(input, emb, Xbf);
  k_transpose<1,1><<<dim3(32, 8),  dim3(32,8), 0, stream>>>(W0,  (void*)W0xT, 256, 1024, 1024, 0);
  k_transpose<1,1><<<dim3(32, 8),  dim3(32,8), 0, stream>>>(W0,  (void*)W0hT, 256, 1024, 1024, 256);
  k_transpose<1,1><<<dim3(32, 16), dim3(32,8), 0, stream>>>(W1,  (void*)W1T,  512, 1024, 1024, 0);
  k_transpose<1,0><<<dim3(500, 8), dim3(32,8), 0, stream>>>(Wsm, (void*)WsT,  256, 16000, 16000, 0);

  // Z0x = X @ W0[:256,:] + b0   (M=8192 r'=(t,b), N=1024 n', K=256); m-major blocks
  k_gemm<0><<<dim3(64, 8), dim3(256), 0, stream>>>(Xbf, W0xT, Z0x, b0, nullptr, nullptr, nullptr);

  // persistent LSTM (24 WGs cooperative; flag-notify dataflow)
  void* kargs[] = { (void*)&Z0x, (void*)&W0hT, (void*)&W1T, (void*)&b1,
                    (void*)&h0h, (void*)&h1h, (void*)&H1bf, (void*)&flag0, (void*)&flag1 };
  hipLaunchCooperativeKernel((void*)k_lstm, dim3(24), dim3(256), kargs, 0, stream);

  // fused projection + log-softmax partials (M=8192 r=(b,t), N=16000, K=256); m-major blocks
  k_gemm<1><<<dim3(64, 125), dim3(256), 0, stream>>>(H1bf, WsT, nullptr, sb, targets, S, LT);

  k_reduce<<<dim3(1), dim3(256), 0, stream>>>(S, LT, (float*)d_out);
}